// Round 1
// baseline (185.398 us; speedup 1.0000x reference)
//
#include <hip/hip_runtime.h>

#define NPTS   8192
#define BATCH  32
#define CIN    64
#define COUT   64
#define RANKK  16
#define ROWS   (BATCH * CIN)   // 2048 = BATCH*COUT too

typedef _Float16 f16;
typedef _Float16 f16x8 __attribute__((ext_vector_type(8)));
typedef float    f32x4 __attribute__((ext_vector_type(4)));

// ---------------------------------------------------------------------------
// Kernel 1: build cos/sin tables in f16.
//   T [c][n]  c<64: cos(2*pi*c*n/N), c>=64: sin(2*pi*(c-64)*n/N)   (for fwd B-frags)
//   Tt[n][c]  transpose of T                                        (for inv B-frags)
// ---------------------------------------------------------------------------
__global__ __launch_bounds__(256) void build_tables(f16* __restrict__ T,
                                                    f16* __restrict__ Tt) {
  __shared__ f16 tile[128][18];  // pad to break transpose bank conflicts
  const int n0 = blockIdx.x * 16;
  const int t = threadIdx.x;
#pragma unroll
  for (int j = 0; j < 8; ++j) {
    int flat = t + 256 * j;          // 0..2047
    int c = flat >> 4, dn = flat & 15;
    int k = c & 63, n = n0 + dn;
    int m = (k * n) & (NPTS - 1);    // arg reduction: k*n mod N
    float ang = (float)m * (6.28318530717958647692f / (float)NPTS);
    float sv, cv;
    sincosf(ang, &sv, &cv);
    tile[c][dn] = (f16)((c < 64) ? cv : sv);
  }
  __syncthreads();
#pragma unroll
  for (int j = 0; j < 8; ++j) {      // write T[c][n] (coalesced in n)
    int flat = t + 256 * j;
    int c = flat >> 4, dn = flat & 15;
    T[(size_t)c * NPTS + n0 + dn] = tile[c][dn];
  }
#pragma unroll
  for (int j = 0; j < 8; ++j) {      // write Tt[n][c] (coalesced in c)
    int flat = t + 256 * j;
    int dn = flat >> 7, c = flat & 127;
    Tt[(size_t)(n0 + dn) * 128 + c] = tile[c][dn];
  }
}

// ---------------------------------------------------------------------------
// Kernel 2: forward "DFT" GEMM, split-K, fp32 partials.
//   Sp[ks][row][c] = sum_{n in seg ks} x[row][n] * T[c][n]
// One wave = 16 rows x 128 cols over one K-segment. x converted fp32->f16 in-reg.
// ---------------------------------------------------------------------------
__global__ __launch_bounds__(256) void fwd_dft(const float* __restrict__ x,
                                               const f16* __restrict__ T,
                                               float* __restrict__ Sp,
                                               int lg_splitk, int kseg) {
  const int wid  = blockIdx.x * 4 + (threadIdx.x >> 6);
  const int lane = threadIdx.x & 63;
  const int ks   = wid & ((1 << lg_splitk) - 1);
  const int rt   = wid >> lg_splitk;          // 0..127 row tile
  const int rl   = lane & 15, hi = lane >> 4;

  const float* xrow = x + (size_t)(rt * 16 + rl) * NPTS + ks * kseg + 8 * hi;
  const f16*   Tb   = T + (size_t)rl * NPTS + ks * kseg + 8 * hi;

  f32x4 acc[8];
#pragma unroll
  for (int i = 0; i < 8; ++i) acc[i] = (f32x4){0.f, 0.f, 0.f, 0.f};

  const int nkt = kseg >> 5;                  // K-steps of 32
  for (int kt = 0; kt < nkt; ++kt) {
    const float* xp = xrow + kt * 32;
    f32x4 a0 = *(const f32x4*)xp;
    f32x4 a1 = *(const f32x4*)(xp + 4);
    f16x8 af;
#pragma unroll
    for (int j = 0; j < 4; ++j) { af[j] = (f16)a0[j]; af[4 + j] = (f16)a1[j]; }
#pragma unroll
    for (int ct = 0; ct < 8; ++ct) {          // 8 col-tiles of 16 (cos0..63,sin0..63)
      f16x8 bf = *(const f16x8*)(Tb + (size_t)ct * 16 * NPTS + kt * 32);
      acc[ct] = __builtin_amdgcn_mfma_f32_16x16x32_f16(af, bf, acc[ct], 0, 0, 0);
    }
  }
  float* out = Sp + ((size_t)ks * ROWS + rt * 16) * 128;
#pragma unroll
  for (int ct = 0; ct < 8; ++ct)
#pragma unroll
    for (int i = 0; i < 4; ++i)
      out[(hi * 4 + i) * 128 + ct * 16 + rl] = acc[ct][i];
}

// ---------------------------------------------------------------------------
// Kernel 3: reduce split-K partials + channel mix + scaling -> Qh (f16).
//   w[i][o]   = sum_r S[r] * (U[i,r] * V[r,o])      (complex)
//   Qr[o][k]  = (c_k/N) sum_i (Sr*wr + Si*wi)
//   Qi[o][k]  = (c_k/N) sum_i (Sr*wi - Si*wr)
//   Qh[row=(b,o)][k]    =  Qr
//   Qh[row=(b,o)][64+k] = -Qi      (so inverse is plain GEMM against T)
// One block per batch b.
// ---------------------------------------------------------------------------
__global__ __launch_bounds__(256) void mix_kernel(const float* __restrict__ Sp,
                                                  const float* __restrict__ Ur,
                                                  const float* __restrict__ Ui,
                                                  const float* __restrict__ Vr,
                                                  const float* __restrict__ Vi,
                                                  const float* __restrict__ Sv,
                                                  f16* __restrict__ Qh,
                                                  int splitk) {
  __shared__ float Srs[64][64], Sis[64][64], wrs[64][64], wis[64][64];
  const int b = blockIdx.x;
  const int t = threadIdx.x;

  // reduce split-K partials into LDS
#pragma unroll
  for (int j = 0; j < 16; ++j) {
    int flat = t + 256 * j;                  // 0..4095
    int i = flat >> 6, k = flat & 63;
    float sr = 0.f, si = 0.f;
    for (int seg = 0; seg < splitk; ++seg) {
      const float* p = Sp + ((size_t)seg * ROWS + (size_t)b * 64 + i) * 128;
      sr += p[k];
      si += p[64 + k];
    }
    Srs[i][k] = sr;
    Sis[i][k] = si;
  }
  // build complex weights w = (U*S)V
#pragma unroll
  for (int j = 0; j < 16; ++j) {
    int flat = t + 256 * j;
    int i = flat >> 6, o = flat & 63;
    float wr = 0.f, wi = 0.f;
    for (int r = 0; r < RANKK; ++r) {
      float ur = Ur[i * RANKK + r], ui = Ui[i * RANKK + r];
      float vr = Vr[r * COUT + o],  vi = Vi[r * COUT + o];
      float s = Sv[r];
      wr += s * (ur * vr - ui * vi);
      wi += s * (ur * vi + ui * vr);
    }
    wrs[i][o] = wr;
    wis[i][o] = wi;
  }
  __syncthreads();

  const int o = t & 63;
  const int kg = t >> 6;
  for (int j = 0; j < 16; ++j) {
    int k = kg * 16 + j;
    float qr = 0.f, qi = 0.f;
    for (int i = 0; i < 64; ++i) {
      float sr = Srs[i][k], si = Sis[i][k];
      float wr = wrs[i][o], wi = wis[i][o];
      qr += sr * wr + si * wi;
      qi += sr * wi - si * wr;
    }
    float sk = (k == 0 ? 1.0f : 2.0f) / (float)NPTS;  // c_k and both ortho 1/sqrt(N)
    f16* qrow = Qh + ((size_t)b * 64 + o) * 128;
    qrow[k]      = (f16)(qr * sk);
    qrow[64 + k] = (f16)(-qi * sk);
  }
}

// ---------------------------------------------------------------------------
// Kernel 4: inverse GEMM.  y[row][n] = sum_{c<128} Qh[row][c] * Tt[n][c]
// One wave = 16 rows x 64 n-cols, K=128 (4 MFMA K-steps x 4 n-subtiles).
// ---------------------------------------------------------------------------
__global__ __launch_bounds__(256) void inv_dft(const f16* __restrict__ Qh,
                                               const f16* __restrict__ Tt,
                                               float* __restrict__ y) {
  const int wid  = blockIdx.x * 4 + (threadIdx.x >> 6);  // 0..16383
  const int lane = threadIdx.x & 63;
  const int rt = wid >> 7;     // 0..127 row tile
  const int nt = wid & 127;    // 0..127 n tile (64 wide)
  const int rl = lane & 15, hi = lane >> 4;

  const f16* qrow = Qh + (size_t)(rt * 16 + rl) * 128 + 8 * hi;
  const f16* tb   = Tt + (size_t)(nt * 64 + rl) * 128 + 8 * hi;

  f32x4 acc[4];
#pragma unroll
  for (int i = 0; i < 4; ++i) acc[i] = (f32x4){0.f, 0.f, 0.f, 0.f};

#pragma unroll
  for (int ksv = 0; ksv < 4; ++ksv) {
    f16x8 af = *(const f16x8*)(qrow + ksv * 32);
#pragma unroll
    for (int s = 0; s < 4; ++s) {
      f16x8 bf = *(const f16x8*)(tb + (size_t)s * 16 * 128 + ksv * 32);
      acc[s] = __builtin_amdgcn_mfma_f32_16x16x32_f16(af, bf, acc[s], 0, 0, 0);
    }
  }
  float* yrow = y + (size_t)(rt * 16 + hi * 4) * NPTS + nt * 64;
#pragma unroll
  for (int s = 0; s < 4; ++s)
#pragma unroll
    for (int i = 0; i < 4; ++i)
      yrow[(size_t)i * NPTS + s * 16 + rl] = acc[s][i];
}

// ---------------------------------------------------------------------------
extern "C" void kernel_launch(void* const* d_in, const int* in_sizes, int n_in,
                              void* d_out, int out_size, void* d_ws, size_t ws_size,
                              hipStream_t stream) {
  const float* x  = (const float*)d_in[0];
  const float* Ur = (const float*)d_in[1];
  const float* Ui = (const float*)d_in[2];
  const float* Vr = (const float*)d_in[3];
  const float* Vi = (const float*)d_in[4];
  const float* Sv = (const float*)d_in[5];
  float* y = (float*)d_out;
  char* ws = (char*)d_ws;

  // pick split-K to fit workspace: 4 MiB tables + splitk MiB partials + 0.5 MiB Qh
  int splitk = 16;
  while (splitk > 1 &&
         (size_t)(4u << 20) + (size_t)splitk * ROWS * 128 * 4 + (size_t)ROWS * 128 * 2 >
             ws_size)
    splitk >>= 1;
  int lg = 0;
  while ((1 << lg) < splitk) ++lg;

  f16*   T  = (f16*)ws;                               // 128*8192*2  = 2 MiB
  f16*   Tt = (f16*)(ws + (2u << 20));                // 8192*128*2  = 2 MiB
  float* Sp = (float*)(ws + (4u << 20));              // splitk * 1 MiB
  f16*   Qh = (f16*)(ws + (4u << 20) +
                     (size_t)splitk * ROWS * 128 * 4);  // 512 KiB

  build_tables<<<NPTS / 16, 256, 0, stream>>>(T, Tt);
  fwd_dft<<<(128 * splitk + 3) / 4, 256, 0, stream>>>(x, T, Sp, lg, NPTS / splitk);
  mix_kernel<<<BATCH, 256, 0, stream>>>(Sp, Ur, Ui, Vr, Vi, Sv, Qh, splitk);
  inv_dft<<<(ROWS / 16) * (NPTS / 64) / 4, 256, 0, stream>>>(Qh, Tt, y);
}

// Round 2
// 106.763 us; speedup vs baseline: 1.7365x; 1.7365x over previous
//
#include <hip/hip_runtime.h>

#define NPTS   8192
#define BATCH  32
#define CIN    64
#define COUT   64
#define RANKK  16
#define ROWS   (BATCH * CIN)   // 2048 = BATCH*COUT too

typedef _Float16 f16;
typedef _Float16 f16x8 __attribute__((ext_vector_type(8)));
typedef float    f32x4 __attribute__((ext_vector_type(4)));

// ---------------------------------------------------------------------------
// Kernel 1: build cos/sin tables in f16.
//   T [c][n]  c<64: cos(2*pi*c*n/N), c>=64: sin(2*pi*(c-64)*n/N)   (for fwd B-frags)
//   Tt[n][c]  transpose of T                                        (for inv B-frags)
// ---------------------------------------------------------------------------
__global__ __launch_bounds__(256) void build_tables(f16* __restrict__ T,
                                                    f16* __restrict__ Tt) {
  __shared__ f16 tile[128][18];  // pad to break transpose bank conflicts
  const int n0 = blockIdx.x * 16;
  const int t = threadIdx.x;
#pragma unroll
  for (int j = 0; j < 8; ++j) {
    int flat = t + 256 * j;          // 0..2047
    int c = flat >> 4, dn = flat & 15;
    int k = c & 63, n = n0 + dn;
    int m = (k * n) & (NPTS - 1);    // arg reduction: k*n mod N
    float ang = (float)m * (6.28318530717958647692f / (float)NPTS);
    float sv, cv;
    sincosf(ang, &sv, &cv);
    tile[c][dn] = (f16)((c < 64) ? cv : sv);
  }
  __syncthreads();
#pragma unroll
  for (int j = 0; j < 8; ++j) {      // write T[c][n] (coalesced in n)
    int flat = t + 256 * j;
    int c = flat >> 4, dn = flat & 15;
    T[(size_t)c * NPTS + n0 + dn] = tile[c][dn];
  }
#pragma unroll
  for (int j = 0; j < 8; ++j) {      // write Tt[n][c] (coalesced in c)
    int flat = t + 256 * j;
    int dn = flat >> 7, c = flat & 127;
    Tt[(size_t)(n0 + dn) * 128 + c] = tile[c][dn];
  }
}

// ---------------------------------------------------------------------------
// Kernel 2: forward "DFT" GEMM, split-K, fp32 partials.
//   Sp[ks][row][c] = sum_{n in seg ks} x[row][n] * T[c][n]
// One wave = 16 rows x 128 cols over one K-segment. x converted fp32->f16 in-reg.
// ---------------------------------------------------------------------------
__global__ __launch_bounds__(256) void fwd_dft(const float* __restrict__ x,
                                               const f16* __restrict__ T,
                                               float* __restrict__ Sp,
                                               int lg_splitk, int kseg) {
  const int wid  = blockIdx.x * 4 + (threadIdx.x >> 6);
  const int lane = threadIdx.x & 63;
  const int ks   = wid & ((1 << lg_splitk) - 1);
  const int rt   = wid >> lg_splitk;          // 0..127 row tile
  const int rl   = lane & 15, hi = lane >> 4;

  const float* xrow = x + (size_t)(rt * 16 + rl) * NPTS + ks * kseg + 8 * hi;
  const f16*   Tb   = T + (size_t)rl * NPTS + ks * kseg + 8 * hi;

  f32x4 acc[8];
#pragma unroll
  for (int i = 0; i < 8; ++i) acc[i] = (f32x4){0.f, 0.f, 0.f, 0.f};

  const int nkt = kseg >> 5;                  // K-steps of 32
  for (int kt = 0; kt < nkt; ++kt) {
    const float* xp = xrow + kt * 32;
    f32x4 a0 = *(const f32x4*)xp;
    f32x4 a1 = *(const f32x4*)(xp + 4);
    f16x8 af;
#pragma unroll
    for (int j = 0; j < 4; ++j) { af[j] = (f16)a0[j]; af[4 + j] = (f16)a1[j]; }
#pragma unroll
    for (int ct = 0; ct < 8; ++ct) {          // 8 col-tiles of 16 (cos0..63,sin0..63)
      f16x8 bf = *(const f16x8*)(Tb + (size_t)ct * 16 * NPTS + kt * 32);
      acc[ct] = __builtin_amdgcn_mfma_f32_16x16x32_f16(af, bf, acc[ct], 0, 0, 0);
    }
  }
  float* out = Sp + ((size_t)ks * ROWS + rt * 16) * 128;
#pragma unroll
  for (int ct = 0; ct < 8; ++ct)
#pragma unroll
    for (int i = 0; i < 4; ++i)
      out[(hi * 4 + i) * 128 + ct * 16 + rl] = acc[ct][i];
}

// ---------------------------------------------------------------------------
// Kernel 3a: split-K partial reduction, fully data-parallel.
//   Sred[row][c] = sum_seg Sp[seg][row][c]   (float4 per thread)
// ---------------------------------------------------------------------------
__global__ __launch_bounds__(256) void reduce_k(const float* __restrict__ Sp,
                                                float* __restrict__ Sred,
                                                int splitk) {
  const int idx = blockIdx.x * 256 + threadIdx.x;      // 0..65535 float4 idx
  const f32x4* src = (const f32x4*)Sp;
  f32x4 acc = src[idx];
  for (int s = 1; s < splitk; ++s)
    acc += src[(size_t)s * (ROWS * 128 / 4) + idx];
  ((f32x4*)Sred)[idx] = acc;
}

// ---------------------------------------------------------------------------
// Kernel 3b: channel mix + scaling -> Qh (f16).  Grid: 32 batches x 16 o-groups.
// Each block: stage S[b] (32 KB) in LDS, recompute w for its 4 o-columns,
// then each thread produces one (o,k) complex output pair.
//   Qh[row=(b,o)][k]    =  (c_k/N) * sum_i (Sr*wr + Si*wi)
//   Qh[row=(b,o)][64+k] = -(c_k/N) * sum_i (Sr*wi - Si*wr)
// ---------------------------------------------------------------------------
__global__ __launch_bounds__(256) void mix3(const float* __restrict__ Sred,
                                            const float* __restrict__ Ur,
                                            const float* __restrict__ Ui,
                                            const float* __restrict__ Vr,
                                            const float* __restrict__ Vi,
                                            const float* __restrict__ Sv,
                                            f16* __restrict__ Qh) {
  __shared__ float Srs[64][64], Sis[64][64];
  __shared__ float wr_s[64][4], wi_s[64][4];
  const int b  = blockIdx.x >> 4;
  const int og = blockIdx.x & 15;
  const int t  = threadIdx.x;

  // stage S[b][i][0..127] -> Srs (cols 0..63) / Sis (cols 64..127)
#pragma unroll
  for (int j = 0; j < 8; ++j) {
    int f4 = t + 256 * j;                // 0..2047 float4s
    int i = f4 >> 5, kc = (f4 & 31) * 4; // row i, col kc..kc+3
    f32x4 v = *(const f32x4*)(Sred + ((size_t)(b * 64 + i)) * 128 + kc);
    if (kc < 64) *(f32x4*)&Srs[i][kc] = v;
    else         *(f32x4*)&Sis[i][kc - 64] = v;
  }

  // recompute w for this block's 4 o-columns: thread t -> (i = t>>2, ol = t&3)
  {
    int i = t >> 2, ol = t & 3, o = og * 4 + ol;
    float wr = 0.f, wi = 0.f;
#pragma unroll
    for (int r = 0; r < RANKK; ++r) {
      float ur = Ur[i * RANKK + r], ui = Ui[i * RANKK + r];
      float vr = Vr[r * COUT + o],  vi = Vi[r * COUT + o];
      float s = Sv[r];
      wr += s * (ur * vr - ui * vi);
      wi += s * (ur * vi + ui * vr);
    }
    wr_s[i][ol] = wr;
    wi_s[i][ol] = wi;
  }
  __syncthreads();

  const int ol = t >> 6, k = t & 63, o = og * 4 + ol;
  float qr = 0.f, qi = 0.f;
#pragma unroll 4
  for (int i = 0; i < 64; ++i) {
    float sr = Srs[i][k], si = Sis[i][k];     // stride-1 across lanes: conflict-free
    float wr = wr_s[i][ol], wi = wi_s[i][ol]; // wave-uniform broadcast
    qr += sr * wr + si * wi;
    qi += sr * wi - si * wr;
  }
  float sk = (k == 0 ? 1.0f : 2.0f) / (float)NPTS;  // c_k and both ortho 1/sqrt(N)
  f16* qrow = Qh + ((size_t)(b * 64 + o)) * 128;
  qrow[k]      = (f16)(qr * sk);
  qrow[64 + k] = (f16)(-qi * sk);
}

// ---------------------------------------------------------------------------
// Kernel 4: inverse GEMM.  y[row][n] = sum_{c<128} Qh[row][c] * Tt[n][c]
// One wave = 16 rows x 64 n-cols, K=128 (4 MFMA K-steps x 4 n-subtiles).
// ---------------------------------------------------------------------------
__global__ __launch_bounds__(256) void inv_dft(const f16* __restrict__ Qh,
                                               const f16* __restrict__ Tt,
                                               float* __restrict__ y) {
  const int wid  = blockIdx.x * 4 + (threadIdx.x >> 6);  // 0..16383
  const int lane = threadIdx.x & 63;
  const int rt = wid >> 7;     // 0..127 row tile
  const int nt = wid & 127;    // 0..127 n tile (64 wide)
  const int rl = lane & 15, hi = lane >> 4;

  const f16* qrow = Qh + (size_t)(rt * 16 + rl) * 128 + 8 * hi;
  const f16* tb   = Tt + (size_t)(nt * 64 + rl) * 128 + 8 * hi;

  f32x4 acc[4];
#pragma unroll
  for (int i = 0; i < 4; ++i) acc[i] = (f32x4){0.f, 0.f, 0.f, 0.f};

#pragma unroll
  for (int ksv = 0; ksv < 4; ++ksv) {
    f16x8 af = *(const f16x8*)(qrow + ksv * 32);
#pragma unroll
    for (int s = 0; s < 4; ++s) {
      f16x8 bf = *(const f16x8*)(tb + (size_t)s * 16 * 128 + ksv * 32);
      acc[s] = __builtin_amdgcn_mfma_f32_16x16x32_f16(af, bf, acc[s], 0, 0, 0);
    }
  }
  float* yrow = y + (size_t)(rt * 16 + hi * 4) * NPTS + nt * 64;
#pragma unroll
  for (int s = 0; s < 4; ++s)
#pragma unroll
    for (int i = 0; i < 4; ++i)
      yrow[(size_t)i * NPTS + s * 16 + rl] = acc[s][i];
}

// ---------------------------------------------------------------------------
extern "C" void kernel_launch(void* const* d_in, const int* in_sizes, int n_in,
                              void* d_out, int out_size, void* d_ws, size_t ws_size,
                              hipStream_t stream) {
  const float* x  = (const float*)d_in[0];
  const float* Ur = (const float*)d_in[1];
  const float* Ui = (const float*)d_in[2];
  const float* Vr = (const float*)d_in[3];
  const float* Vi = (const float*)d_in[4];
  const float* Sv = (const float*)d_in[5];
  float* y = (float*)d_out;
  char* ws = (char*)d_ws;

  // workspace: 4 MiB tables + splitk MiB partials + 1 MiB Sred + 0.5 MiB Qh
  int splitk = 16;
  while (splitk > 1 &&
         (size_t)(4u << 20) + (size_t)splitk * ROWS * 128 * 4 +
                 (size_t)ROWS * 128 * 4 + (size_t)ROWS * 128 * 2 >
             ws_size)
    splitk >>= 1;
  int lg = 0;
  while ((1 << lg) < splitk) ++lg;

  f16*   T    = (f16*)ws;                              // 2 MiB
  f16*   Tt   = (f16*)(ws + (2u << 20));               // 2 MiB
  float* Sp   = (float*)(ws + (4u << 20));             // splitk * 1 MiB
  char*  p    = ws + (4u << 20) + (size_t)splitk * ROWS * 128 * 4;
  float* Sred = (float*)p;                             // 1 MiB
  f16*   Qh   = (f16*)(p + (size_t)ROWS * 128 * 4);    // 512 KiB

  build_tables<<<NPTS / 16, 256, 0, stream>>>(T, Tt);
  fwd_dft<<<(128 * splitk + 3) / 4, 256, 0, stream>>>(x, T, Sp, lg, NPTS / splitk);
  reduce_k<<<ROWS * 128 / 4 / 256, 256, 0, stream>>>(Sp, Sred, splitk);
  mix3<<<BATCH * 16, 256, 0, stream>>>(Sred, Ur, Ui, Vr, Vi, Sv, Qh);
  inv_dft<<<(ROWS / 16) * (NPTS / 64) / 4, 256, 0, stream>>>(Qh, Tt, y);
}

// Round 5
// 103.793 us; speedup vs baseline: 1.7862x; 1.0286x over previous
//
#include <hip/hip_runtime.h>

#define NPTS   8192
#define BATCH  32
#define CIN    64
#define COUT   64
#define RANKK  16
#define ROWS   (BATCH * CIN)   // 2048 = BATCH*COUT too
#define KB_SPLIT 16            // outer K split (Sp segments)

typedef _Float16 f16;
typedef _Float16 f16x8 __attribute__((ext_vector_type(8)));
typedef float    f32x4 __attribute__((ext_vector_type(4)));

// ---------------------------------------------------------------------------
// Kernel 1: build cos/sin tables in f16.
//   T [c][n]  c<64: cos(2*pi*c*n/N), c>=64: sin(2*pi*(c-64)*n/N)   (for fwd B-frags)
//   Tt[n][c]  transpose of T                                        (for inv B-frags)
// ---------------------------------------------------------------------------
__global__ __launch_bounds__(256) void build_tables(f16* __restrict__ T,
                                                    f16* __restrict__ Tt) {
  __shared__ f16 tile[128][18];  // pad to break transpose bank conflicts
  const int n0 = blockIdx.x * 16;
  const int t = threadIdx.x;
#pragma unroll
  for (int j = 0; j < 8; ++j) {
    int flat = t + 256 * j;          // 0..2047
    int c = flat >> 4, dn = flat & 15;
    int k = c & 63, n = n0 + dn;
    int m = (k * n) & (NPTS - 1);    // arg reduction: k*n mod N
    float ang = (float)m * (6.28318530717958647692f / (float)NPTS);
    float sv, cv;
    sincosf(ang, &sv, &cv);
    tile[c][dn] = (f16)((c < 64) ? cv : sv);
  }
  __syncthreads();
#pragma unroll
  for (int j = 0; j < 8; ++j) {      // write T[c][n] (coalesced in n)
    int flat = t + 256 * j;
    int c = flat >> 4, dn = flat & 15;
    T[(size_t)c * NPTS + n0 + dn] = tile[c][dn];
  }
#pragma unroll
  for (int j = 0; j < 8; ++j) {      // write Tt[n][c] (coalesced in c)
    int flat = t + 256 * j;
    int dn = flat >> 7, c = flat & 127;
    Tt[(size_t)(n0 + dn) * 128 + c] = tile[c][dn];
  }
}

// ---------------------------------------------------------------------------
// Kernel 2: forward "DFT" GEMM.
//   Sp[kb][row][c] = sum_{n in K-block kb} x[row][n] * T[c][n]
// Grid = 128 row-tiles x 16 K-blocks; block = 4 waves, each wave one 128-wide
// K-sub-segment of the same 16 rows; LDS tree-reduce 4 partials -> Sp[kb].
// ---------------------------------------------------------------------------
__global__ __launch_bounds__(256) void fwd_dft(const float* __restrict__ x,
                                               const f16* __restrict__ T,
                                               float* __restrict__ Sp) {
  __shared__ float red[2][16][132];  // pad 132: LDS banks spread, 2-way max
  const int w    = threadIdx.x >> 6;
  const int lane = threadIdx.x & 63;
  const int kb   = blockIdx.x & (KB_SPLIT - 1);
  const int rt   = blockIdx.x >> 4;            // 0..127 row tile
  const int rl = lane & 15, hi = lane >> 4;
  const int k0 = kb * (NPTS / KB_SPLIT) + w * 128;

  const float* xrow = x + (size_t)(rt * 16 + rl) * NPTS + k0 + 8 * hi;
  const f16*   Tb   = T + (size_t)rl * NPTS + k0 + 8 * hi;

  f32x4 acc[8];
#pragma unroll
  for (int i = 0; i < 8; ++i) acc[i] = (f32x4){0.f, 0.f, 0.f, 0.f};

#pragma unroll
  for (int kt = 0; kt < 4; ++kt) {             // 4 K-steps of 32
    const float* xp = xrow + kt * 32;
    f32x4 a0 = *(const f32x4*)xp;
    f32x4 a1 = *(const f32x4*)(xp + 4);
    f16x8 af;
#pragma unroll
    for (int j = 0; j < 4; ++j) { af[j] = (f16)a0[j]; af[4 + j] = (f16)a1[j]; }
#pragma unroll
    for (int ct = 0; ct < 8; ++ct) {           // 8 col-tiles (cos0..63,sin0..63)
      f16x8 bf = *(const f16x8*)(Tb + (size_t)ct * 16 * NPTS + kt * 32);
      acc[ct] = __builtin_amdgcn_mfma_f32_16x16x32_f16(af, bf, acc[ct], 0, 0, 0);
    }
  }

  // tree-reduce the 4 per-wave partials (C/D map: row = hi*4+i, col = ct*16+rl)
  if (w >= 2) {
#pragma unroll
    for (int ct = 0; ct < 8; ++ct)
#pragma unroll
      for (int i = 0; i < 4; ++i)
        red[w - 2][hi * 4 + i][ct * 16 + rl] = acc[ct][i];
  }
  __syncthreads();
  if (w < 2) {
#pragma unroll
    for (int ct = 0; ct < 8; ++ct)
#pragma unroll
      for (int i = 0; i < 4; ++i)
        acc[ct][i] += red[w][hi * 4 + i][ct * 16 + rl];
  }
  __syncthreads();
  if (w == 1) {
#pragma unroll
    for (int ct = 0; ct < 8; ++ct)
#pragma unroll
      for (int i = 0; i < 4; ++i)
        red[0][hi * 4 + i][ct * 16 + rl] = acc[ct][i];
  }
  __syncthreads();
  if (w == 0) {
    float* out = Sp + ((size_t)kb * ROWS + rt * 16) * 128;
#pragma unroll
    for (int ct = 0; ct < 8; ++ct)
#pragma unroll
      for (int i = 0; i < 4; ++i)
        out[(hi * 4 + i) * 128 + ct * 16 + rl] =
            acc[ct][i] + red[0][hi * 4 + i][ct * 16 + rl];
  }
}

// ---------------------------------------------------------------------------
// Kernel 3a: split-K partial reduction, fully data-parallel.
//   Sred[row][c] = sum_seg Sp[seg][row][c]   (float4 per thread)
// ---------------------------------------------------------------------------
__global__ __launch_bounds__(256) void reduce_k(const float* __restrict__ Sp,
                                                float* __restrict__ Sred) {
  const int idx = blockIdx.x * 256 + threadIdx.x;      // 0..65535 float4 idx
  const f32x4* src = (const f32x4*)Sp;
  f32x4 acc = src[idx];
#pragma unroll
  for (int s = 1; s < KB_SPLIT; ++s)
    acc += src[(size_t)s * (ROWS * 128 / 4) + idx];
  ((f32x4*)Sred)[idx] = acc;
}

// ---------------------------------------------------------------------------
// Kernel 3b: channel mix + scaling -> Qh (f16).  Grid: 32 batches x 16 o-groups.
// Each block: stage S[b] (32 KB) in LDS, recompute w for its 4 o-columns,
// then each thread produces one (o,k) complex output pair.
//   Qh[row=(b,o)][k]    =  (c_k/N) * sum_i (Sr*wr + Si*wi)
//   Qh[row=(b,o)][64+k] = -(c_k/N) * sum_i (Sr*wi - Si*wr)
// ---------------------------------------------------------------------------
__global__ __launch_bounds__(256) void mix3(const float* __restrict__ Sred,
                                            const float* __restrict__ Ur,
                                            const float* __restrict__ Ui,
                                            const float* __restrict__ Vr,
                                            const float* __restrict__ Vi,
                                            const float* __restrict__ Sv,
                                            f16* __restrict__ Qh) {
  __shared__ float Srs[64][64], Sis[64][64];
  __shared__ float wr_s[64][4], wi_s[64][4];
  const int b  = blockIdx.x >> 4;
  const int og = blockIdx.x & 15;
  const int t  = threadIdx.x;

  // stage S[b][i][0..127] -> Srs (cols 0..63) / Sis (cols 64..127)
#pragma unroll
  for (int j = 0; j < 8; ++j) {
    int f4 = t + 256 * j;                // 0..2047 float4s
    int i = f4 >> 5, kc = (f4 & 31) * 4; // row i, col kc..kc+3
    f32x4 v = *(const f32x4*)(Sred + ((size_t)(b * 64 + i)) * 128 + kc);
    if (kc < 64) *(f32x4*)&Srs[i][kc] = v;
    else         *(f32x4*)&Sis[i][kc - 64] = v;
  }

  // recompute w for this block's 4 o-columns: thread t -> (i = t>>2, ol = t&3)
  {
    int i = t >> 2, ol = t & 3, o = og * 4 + ol;
    float wr = 0.f, wi = 0.f;
#pragma unroll
    for (int r = 0; r < RANKK; ++r) {
      float ur = Ur[i * RANKK + r], ui = Ui[i * RANKK + r];
      float vr = Vr[r * COUT + o],  vi = Vi[r * COUT + o];
      float s = Sv[r];
      wr += s * (ur * vr - ui * vi);
      wi += s * (ur * vi + ui * vr);
    }
    wr_s[i][ol] = wr;
    wi_s[i][ol] = wi;
  }
  __syncthreads();

  const int ol = t >> 6, k = t & 63, o = og * 4 + ol;
  float qr = 0.f, qi = 0.f;
#pragma unroll 4
  for (int i = 0; i < 64; ++i) {
    float sr = Srs[i][k], si = Sis[i][k];     // stride-1 across lanes: conflict-free
    float wr = wr_s[i][ol], wi = wi_s[i][ol]; // wave-uniform broadcast
    qr += sr * wr + si * wi;
    qi += sr * wi - si * wr;
  }
  float sk = (k == 0 ? 1.0f : 2.0f) / (float)NPTS;  // c_k and both ortho 1/sqrt(N)
  f16* qrow = Qh + ((size_t)(b * 64 + o)) * 128;
  qrow[k]      = (f16)(qr * sk);
  qrow[64 + k] = (f16)(-qi * sk);
}

// ---------------------------------------------------------------------------
// Kernel 4: inverse GEMM.  y[row][n] = sum_{c<128} Qh[row][c] * Tt[n][c]
// One wave = 16 rows x 64 n-cols, K=128 (4 MFMA K-steps x 4 n-subtiles).
// ---------------------------------------------------------------------------
__global__ __launch_bounds__(256) void inv_dft(const f16* __restrict__ Qh,
                                               const f16* __restrict__ Tt,
                                               float* __restrict__ y) {
  const int wid  = blockIdx.x * 4 + (threadIdx.x >> 6);  // 0..16383
  const int lane = threadIdx.x & 63;
  const int rt = wid >> 7;     // 0..127 row tile
  const int nt = wid & 127;    // 0..127 n tile (64 wide)
  const int rl = lane & 15, hi = lane >> 4;

  const f16* qrow = Qh + (size_t)(rt * 16 + rl) * 128 + 8 * hi;
  const f16* tb   = Tt + (size_t)(nt * 64 + rl) * 128 + 8 * hi;

  f32x4 acc[4];
#pragma unroll
  for (int i = 0; i < 4; ++i) acc[i] = (f32x4){0.f, 0.f, 0.f, 0.f};

#pragma unroll
  for (int ksv = 0; ksv < 4; ++ksv) {
    f16x8 af = *(const f16x8*)(qrow + ksv * 32);
#pragma unroll
    for (int s = 0; s < 4; ++s) {
      f16x8 bf = *(const f16x8*)(tb + (size_t)s * 16 * 128 + ksv * 32);
      acc[s] = __builtin_amdgcn_mfma_f32_16x16x32_f16(af, bf, acc[s], 0, 0, 0);
    }
  }
  float* yrow = y + (size_t)(rt * 16 + hi * 4) * NPTS + nt * 64;
#pragma unroll
  for (int s = 0; s < 4; ++s)
#pragma unroll
    for (int i = 0; i < 4; ++i)
      yrow[(size_t)i * NPTS + s * 16 + rl] = acc[s][i];
}

// ---------------------------------------------------------------------------
extern "C" void kernel_launch(void* const* d_in, const int* in_sizes, int n_in,
                              void* d_out, int out_size, void* d_ws, size_t ws_size,
                              hipStream_t stream) {
  const float* x  = (const float*)d_in[0];
  const float* Ur = (const float*)d_in[1];
  const float* Ui = (const float*)d_in[2];
  const float* Vr = (const float*)d_in[3];
  const float* Vi = (const float*)d_in[4];
  const float* Sv = (const float*)d_in[5];
  float* y = (float*)d_out;
  char* ws = (char*)d_ws;

  // workspace layout (21.5 MiB total, verified to fit in prior rounds):
  f16*   T    = (f16*)ws;                              // 2 MiB
  f16*   Tt   = (f16*)(ws + (2u << 20));               // 2 MiB
  float* Sp   = (float*)(ws + (4u << 20));             // KB_SPLIT * 1 MiB
  char*  p    = ws + (4u << 20) + (size_t)KB_SPLIT * ROWS * 128 * 4;
  float* Sred = (float*)p;                             // 1 MiB
  f16*   Qh   = (f16*)(p + (size_t)ROWS * 128 * 4);    // 512 KiB

  build_tables<<<NPTS / 16, 256, 0, stream>>>(T, Tt);
  fwd_dft<<<128 * KB_SPLIT, 256, 0, stream>>>(x, T, Sp);
  reduce_k<<<ROWS * 128 / 4 / 256, 256, 0, stream>>>(Sp, Sred);
  mix3<<<BATCH * 16, 256, 0, stream>>>(Sred, Ur, Ui, Vr, Vi, Sv, Qh);
  inv_dft<<<(ROWS / 16) * (NPTS / 64) / 4, 256, 0, stream>>>(Qh, Tt, y);
}

// Round 7
// 77.636 us; speedup vs baseline: 2.3880x; 1.3369x over previous
//
#include <hip/hip_runtime.h>

#define NPTS   8192
#define BATCH  32
#define CIN    64
#define COUT   64
#define RANKK  16
#define ROWS   (BATCH * CIN)   // 2048 = BATCH*COUT too
#define KB_SPLIT 16            // outer K split (Sp segments)

typedef _Float16 f16;
typedef _Float16 f16x8 __attribute__((ext_vector_type(8)));
typedef float    f32x4 __attribute__((ext_vector_type(4)));

__device__ __forceinline__ void gload16(const void* g, void* l) {
  __builtin_amdgcn_global_load_lds(
      (const __attribute__((address_space(1))) void*)g,
      (__attribute__((address_space(3))) void*)l, 16, 0, 0);
}

// ---------------------------------------------------------------------------
// Kernel 1: build cos/sin tables in f16.
//   T [c][n]  c<64: cos(2*pi*c*n/N), c>=64: sin(2*pi*(c-64)*n/N)   (for fwd B-frags)
//   Tt[n][c]  transpose of T                                        (for inv B-frags)
// ---------------------------------------------------------------------------
__global__ __launch_bounds__(256) void build_tables(f16* __restrict__ T,
                                                    f16* __restrict__ Tt) {
  __shared__ f16 tile[128][18];  // pad to break transpose bank conflicts
  const int n0 = blockIdx.x * 16;
  const int t = threadIdx.x;
#pragma unroll
  for (int j = 0; j < 8; ++j) {
    int flat = t + 256 * j;          // 0..2047
    int c = flat >> 4, dn = flat & 15;
    int k = c & 63, n = n0 + dn;
    int m = (k * n) & (NPTS - 1);    // arg reduction: k*n mod N
    float ang = (float)m * (6.28318530717958647692f / (float)NPTS);
    float sv, cv;
    sincosf(ang, &sv, &cv);
    tile[c][dn] = (f16)((c < 64) ? cv : sv);
  }
  __syncthreads();
#pragma unroll
  for (int j = 0; j < 8; ++j) {      // write T[c][n] (coalesced in n)
    int flat = t + 256 * j;
    int c = flat >> 4, dn = flat & 15;
    T[(size_t)c * NPTS + n0 + dn] = tile[c][dn];
  }
#pragma unroll
  for (int j = 0; j < 8; ++j) {      // write Tt[n][c] (coalesced in c)
    int flat = t + 256 * j;
    int dn = flat >> 7, c = flat & 127;
    Tt[(size_t)(n0 + dn) * 128 + c] = tile[c][dn];
  }
}

// ---------------------------------------------------------------------------
// Kernel 2: forward "DFT" GEMM, LDS-staged, depth-2 async pipeline.
//   Sp[kb][row][c] = sum_{n in K-block kb} x[row][n] * T[c][n]
// Grid = 32 row-blocks(64 rows) x 16 kb. Block: 4 waves, C-tile 64x128,
// K-range 512 in 16 steps of 32. Staging: global_load_lds w16, 3 LDS slots,
// counted vmcnt(4). LDS XOR-swizzled (pre-swizzled global src + swz read).
// Per K-step per block: x-tile 64x32 f32 (8 KiB) + T-tile 128x32 f16 (8 KiB)
// = 4 gload16 per thread exactly (vmcnt accounting depends on this).
// ---------------------------------------------------------------------------
__global__ __launch_bounds__(256) void fwd_dft(const float* __restrict__ x,
                                               const f16* __restrict__ T,
                                               float* __restrict__ Sp) {
  __shared__ __align__(16) char lds[3 * 16384];  // 3 slots x (8K x + 8K T)
  const int t    = threadIdx.x;
  const int w    = t >> 6;
  const int lane = t & 63;
  const int rl = lane & 15, hi = lane >> 4;
  const int kb = blockIdx.x & (KB_SPLIT - 1);
  const int r0 = (blockIdx.x >> 4) * 64;       // row-block base
  const int k0 = kb * (NPTS / KB_SPLIT);       // 512-wide K range

  // dest chunk -> pre-swizzled global source (involution: c^row-bits)
  const int xc0 = t, xc1 = t + 256;            // x chunks (row=c>>3, cc=c&7)
  const int tc0 = t, tc1 = t + 256;            // T chunks (row=c>>2, cc=c&3)
  const int xr0_ = xc0 >> 3, xr1_ = xc1 >> 3;
  const int tr0_ = tc0 >> 2, tr1_ = tc1 >> 2;
  const int xo0 = ((xc0 & 7) ^ (xr0_ & 7)) << 2;  // float offset in 32-col step
  const int xo1 = ((xc1 & 7) ^ (xr1_ & 7)) << 2;
  const int to0 = ((tc0 & 3) ^ (tr0_ & 3)) << 3;  // f16 offset
  const int to1 = ((tc1 & 3) ^ (tr1_ & 3)) << 3;
  const float* xs0 = x + (size_t)(r0 + xr0_) * NPTS + k0 + xo0;
  const float* xs1 = x + (size_t)(r0 + xr1_) * NPTS + k0 + xo1;
  const f16*   ts0 = T + (size_t)tr0_ * NPTS + k0 + to0;
  const f16*   ts1 = T + (size_t)tr1_ * NPTS + k0 + to1;
  const int wu = w * 64 * 16;                  // wave-uniform LDS byte base

  auto STAGE = [&](int kt, int slot) {
    char* xb = lds + slot * 16384;
    char* tb = xb + 8192;
    const int kk = kt * 32;
    gload16(xs0 + kk, xb + wu);
    gload16(xs1 + kk, xb + 4096 + wu);
    gload16(ts0 + kk, tb + wu);
    gload16(ts1 + kk, tb + 4096 + wu);
  };

  f32x4 acc[8];
#pragma unroll
  for (int i = 0; i < 8; ++i) acc[i] = (f32x4){0.f, 0.f, 0.f, 0.f};

  // swizzled read offsets (lane-constant across kt)
  const int axr = w * 16 + rl;  // x_tile row for this lane's A fragment
  const int ad0 = (axr * 8 + ((2 * hi) ^ (axr & 7))) * 16;
  const int ad1 = (axr * 8 + ((2 * hi + 1) ^ (axr & 7))) * 16;
  int bd[8];
#pragma unroll
  for (int ct = 0; ct < 8; ++ct) {
    int trow = ct * 16 + rl;
    bd[ct] = (trow * 4 + (hi ^ (trow & 3))) * 16;
  }

  auto COMPUTE = [&](int slot) {
    char* xb = lds + slot * 16384;
    char* tb = xb + 8192;
    f32x4 a0 = *(const f32x4*)(xb + ad0);
    f32x4 a1 = *(const f32x4*)(xb + ad1);
    f16x8 af;
#pragma unroll
    for (int j = 0; j < 4; ++j) { af[j] = (f16)a0[j]; af[4 + j] = (f16)a1[j]; }
#pragma unroll
    for (int ct = 0; ct < 8; ++ct) {
      f16x8 bf = *(const f16x8*)(tb + bd[ct]);
      acc[ct] = __builtin_amdgcn_mfma_f32_16x16x32_f16(af, bf, acc[ct], 0, 0, 0);
    }
  };

  STAGE(0, 0);
  STAGE(1, 1);
  asm volatile("s_waitcnt vmcnt(4)" ::: "memory");  // slot0 landed; slot1 in flight
  __builtin_amdgcn_s_barrier();

  int sc = 0, ss = 2;  // compute slot, stage slot
  for (int kt = 0; kt < 16; ++kt) {
    if (kt + 2 < 16) STAGE(kt + 2, ss);
    COMPUTE(sc);
    if (kt < 15) {
      if (kt + 2 < 16)
        asm volatile("s_waitcnt vmcnt(4)" ::: "memory");  // next slot landed
      else
        asm volatile("s_waitcnt vmcnt(0)" ::: "memory");  // drain final stage
      __builtin_amdgcn_s_barrier();
    }
    sc = (sc == 2) ? 0 : sc + 1;
    ss = (ss == 2) ? 0 : ss + 1;
  }

  // epilogue: wave w owns rows r0+w*16..+16 (C/D map: row=hi*4+i, col=ct*16+rl)
  float* out = Sp + ((size_t)kb * ROWS + r0 + w * 16) * 128;
#pragma unroll
  for (int ct = 0; ct < 8; ++ct)
#pragma unroll
    for (int i = 0; i < 4; ++i)
      out[(hi * 4 + i) * 128 + ct * 16 + rl] = acc[ct][i];
}

// ---------------------------------------------------------------------------
// Kernel 3a: split-K partial reduction, fully data-parallel.
// ---------------------------------------------------------------------------
__global__ __launch_bounds__(256) void reduce_k(const float* __restrict__ Sp,
                                                float* __restrict__ Sred) {
  const int idx = blockIdx.x * 256 + threadIdx.x;      // 0..65535 float4 idx
  const f32x4* src = (const f32x4*)Sp;
  f32x4 acc = src[idx];
#pragma unroll
  for (int s = 1; s < KB_SPLIT; ++s)
    acc += src[(size_t)s * (ROWS * 128 / 4) + idx];
  ((f32x4*)Sred)[idx] = acc;
}

// ---------------------------------------------------------------------------
// Kernel 3b: channel mix + scaling -> Qh (f16).  Grid: 32 batches x 16 o-groups.
// ---------------------------------------------------------------------------
__global__ __launch_bounds__(256) void mix3(const float* __restrict__ Sred,
                                            const float* __restrict__ Ur,
                                            const float* __restrict__ Ui,
                                            const float* __restrict__ Vr,
                                            const float* __restrict__ Vi,
                                            const float* __restrict__ Sv,
                                            f16* __restrict__ Qh) {
  __shared__ float Srs[64][64], Sis[64][64];
  __shared__ float wr_s[64][4], wi_s[64][4];
  const int b  = blockIdx.x >> 4;
  const int og = blockIdx.x & 15;
  const int t  = threadIdx.x;

#pragma unroll
  for (int j = 0; j < 8; ++j) {
    int f4 = t + 256 * j;                // 0..2047 float4s
    int i = f4 >> 5, kc = (f4 & 31) * 4; // row i, col kc..kc+3
    f32x4 v = *(const f32x4*)(Sred + ((size_t)(b * 64 + i)) * 128 + kc);
    if (kc < 64) *(f32x4*)&Srs[i][kc] = v;
    else         *(f32x4*)&Sis[i][kc - 64] = v;
  }

  {
    int i = t >> 2, ol = t & 3, o = og * 4 + ol;
    float wr = 0.f, wi = 0.f;
#pragma unroll
    for (int r = 0; r < RANKK; ++r) {
      float ur = Ur[i * RANKK + r], ui = Ui[i * RANKK + r];
      float vr = Vr[r * COUT + o],  vi = Vi[r * COUT + o];
      float s = Sv[r];
      wr += s * (ur * vr - ui * vi);
      wi += s * (ur * vi + ui * vr);
    }
    wr_s[i][ol] = wr;
    wi_s[i][ol] = wi;
  }
  __syncthreads();

  const int ol = t >> 6, k = t & 63, o = og * 4 + ol;
  float qr = 0.f, qi = 0.f;
#pragma unroll 4
  for (int i = 0; i < 64; ++i) {
    float sr = Srs[i][k], si = Sis[i][k];     // stride-1 across lanes: conflict-free
    float wr = wr_s[i][ol], wi = wi_s[i][ol]; // wave-uniform broadcast
    qr += sr * wr + si * wi;
    qi += sr * wi - si * wr;
  }
  float sk = (k == 0 ? 1.0f : 2.0f) / (float)NPTS;  // c_k and both ortho 1/sqrt(N)
  f16* qrow = Qh + ((size_t)(b * 64 + o)) * 128;
  qrow[k]      = (f16)(qr * sk);
  qrow[64 + k] = (f16)(-qi * sk);
}

// ---------------------------------------------------------------------------
// Kernel 4: inverse GEMM.  y[row][n] = sum_{c<128} Qh[row][c] * Tt[n][c]
// ---------------------------------------------------------------------------
__global__ __launch_bounds__(256) void inv_dft(const f16* __restrict__ Qh,
                                               const f16* __restrict__ Tt,
                                               float* __restrict__ y) {
  const int wid  = blockIdx.x * 4 + (threadIdx.x >> 6);  // 0..16383
  const int lane = threadIdx.x & 63;
  const int rt = wid >> 7;     // 0..127 row tile
  const int nt = wid & 127;    // 0..127 n tile (64 wide)
  const int rl = lane & 15, hi = lane >> 4;

  const f16* qrow = Qh + (size_t)(rt * 16 + rl) * 128 + 8 * hi;
  const f16* tb   = Tt + (size_t)(nt * 64 + rl) * 128 + 8 * hi;

  f32x4 acc[4];
#pragma unroll
  for (int i = 0; i < 4; ++i) acc[i] = (f32x4){0.f, 0.f, 0.f, 0.f};

#pragma unroll
  for (int ksv = 0; ksv < 4; ++ksv) {
    f16x8 af = *(const f16x8*)(qrow + ksv * 32);
#pragma unroll
    for (int s = 0; s < 4; ++s) {
      f16x8 bf = *(const f16x8*)(tb + (size_t)s * 16 * 128 + ksv * 32);
      acc[s] = __builtin_amdgcn_mfma_f32_16x16x32_f16(af, bf, acc[s], 0, 0, 0);
    }
  }
  float* yrow = y + (size_t)(rt * 16 + hi * 4) * NPTS + nt * 64;
#pragma unroll
  for (int s = 0; s < 4; ++s)
#pragma unroll
    for (int i = 0; i < 4; ++i)
      yrow[(size_t)i * NPTS + s * 16 + rl] = acc[s][i];
}

// ---------------------------------------------------------------------------
extern "C" void kernel_launch(void* const* d_in, const int* in_sizes, int n_in,
                              void* d_out, int out_size, void* d_ws, size_t ws_size,
                              hipStream_t stream) {
  const float* x  = (const float*)d_in[0];
  const float* Ur = (const float*)d_in[1];
  const float* Ui = (const float*)d_in[2];
  const float* Vr = (const float*)d_in[3];
  const float* Vi = (const float*)d_in[4];
  const float* Sv = (const float*)d_in[5];
  float* y = (float*)d_out;
  char* ws = (char*)d_ws;

  // workspace layout (21.5 MiB total, verified to fit in prior rounds):
  f16*   T    = (f16*)ws;                              // 2 MiB
  f16*   Tt   = (f16*)(ws + (2u << 20));               // 2 MiB
  float* Sp   = (float*)(ws + (4u << 20));             // KB_SPLIT * 1 MiB
  char*  p    = ws + (4u << 20) + (size_t)KB_SPLIT * ROWS * 128 * 4;
  float* Sred = (float*)p;                             // 1 MiB
  f16*   Qh   = (f16*)(p + (size_t)ROWS * 128 * 4);    // 512 KiB

  build_tables<<<NPTS / 16, 256, 0, stream>>>(T, Tt);
  fwd_dft<<<(ROWS / 64) * KB_SPLIT, 256, 0, stream>>>(x, T, Sp);
  reduce_k<<<ROWS * 128 / 4 / 256, 256, 0, stream>>>(Sp, Sred);
  mix3<<<BATCH * 16, 256, 0, stream>>>(Sred, Ur, Ui, Vr, Vi, Sv, Qh);
  inv_dft<<<(ROWS / 16) * (NPTS / 64) / 4, 256, 0, stream>>>(Qh, Tt, y);
}

// Round 11
// 52.059 us; speedup vs baseline: 3.5613x; 1.4913x over previous
//
#include <hip/hip_runtime.h>

#define NPTS   8192
#define BATCH  32
#define CIN    64
#define COUT   64
#define RANKK  16
#define ROWS   (BATCH * CIN)   // 2048 = BATCH*COUT too
#define KB_SPLIT 16            // outer K split (Sp segments)

typedef _Float16 f16;
typedef _Float16 f16x8 __attribute__((ext_vector_type(8)));
typedef float    f32x4 __attribute__((ext_vector_type(4)));

__device__ __forceinline__ void gload16(const void* g, void* l) {
  __builtin_amdgcn_global_load_lds(
      (const __attribute__((address_space(1))) void*)g,
      (__attribute__((address_space(3))) void*)l, 16, 0, 0);
}

// ---------------------------------------------------------------------------
// Kernel 1: build cos/sin tables in f16.
//   T [c][n]  c<64: cos(2*pi*c*n/N), c>=64: sin(2*pi*(c-64)*n/N)   (for fwd B-frags)
//   Tt[n][c]  transpose of T                                        (for inv B-frags)
// ---------------------------------------------------------------------------
__global__ __launch_bounds__(256) void build_tables(f16* __restrict__ T,
                                                    f16* __restrict__ Tt) {
  __shared__ f16 tile[128][18];  // pad to break transpose bank conflicts
  const int n0 = blockIdx.x * 16;
  const int t = threadIdx.x;
#pragma unroll
  for (int j = 0; j < 8; ++j) {
    int flat = t + 256 * j;          // 0..2047
    int c = flat >> 4, dn = flat & 15;
    int k = c & 63, n = n0 + dn;
    int m = (k * n) & (NPTS - 1);    // arg reduction: k*n mod N
    float ang = (float)m * (6.28318530717958647692f / (float)NPTS);
    float sv, cv;
    sincosf(ang, &sv, &cv);
    tile[c][dn] = (f16)((c < 64) ? cv : sv);
  }
  __syncthreads();
#pragma unroll
  for (int j = 0; j < 8; ++j) {      // write T[c][n] (coalesced in n)
    int flat = t + 256 * j;
    int c = flat >> 4, dn = flat & 15;
    T[(size_t)c * NPTS + n0 + dn] = tile[c][dn];
  }
#pragma unroll
  for (int j = 0; j < 8; ++j) {      // write Tt[n][c] (coalesced in c)
    int flat = t + 256 * j;
    int dn = flat >> 7, c = flat & 127;
    Tt[(size_t)(n0 + dn) * 128 + c] = tile[c][dn];
  }
}

// ---------------------------------------------------------------------------
// Kernel 2: forward "DFT" GEMM, LDS-staged, depth-2 async pipeline.
//   Sp[kb][row][c] = sum_{n in K-block kb} x[row][n] * T[c][n]
// Grid = 32 row-blocks(64 rows) x 16 kb. Block: 4 waves, C-tile 64x128,
// K-range 512 in 16 steps of 32. Staging: global_load_lds w16, 3 LDS slots,
// counted vmcnt(4). LDS XOR-swizzled (pre-swizzled global src + swz read).
// (unchanged from R7 — verified PASS)
// ---------------------------------------------------------------------------
__global__ __launch_bounds__(256) void fwd_dft(const float* __restrict__ x,
                                               const f16* __restrict__ T,
                                               float* __restrict__ Sp) {
  __shared__ __align__(16) char lds[3 * 16384];  // 3 slots x (8K x + 8K T)
  const int t    = threadIdx.x;
  const int w    = t >> 6;
  const int lane = t & 63;
  const int rl = lane & 15, hi = lane >> 4;
  const int kb = blockIdx.x & (KB_SPLIT - 1);
  const int r0 = (blockIdx.x >> 4) * 64;       // row-block base
  const int k0 = kb * (NPTS / KB_SPLIT);       // 512-wide K range

  // dest chunk -> pre-swizzled global source (involution: c^row-bits)
  const int xc0 = t, xc1 = t + 256;            // x chunks (row=c>>3, cc=c&7)
  const int tc0 = t, tc1 = t + 256;            // T chunks (row=c>>2, cc=c&3)
  const int xr0_ = xc0 >> 3, xr1_ = xc1 >> 3;
  const int tr0_ = tc0 >> 2, tr1_ = tc1 >> 2;
  const int xo0 = ((xc0 & 7) ^ (xr0_ & 7)) << 2;  // float offset in 32-col step
  const int xo1 = ((xc1 & 7) ^ (xr1_ & 7)) << 2;
  const int to0 = ((tc0 & 3) ^ (tr0_ & 3)) << 3;  // f16 offset
  const int to1 = ((tc1 & 3) ^ (tr1_ & 3)) << 3;
  const float* xs0 = x + (size_t)(r0 + xr0_) * NPTS + k0 + xo0;
  const float* xs1 = x + (size_t)(r0 + xr1_) * NPTS + k0 + xo1;
  const f16*   ts0 = T + (size_t)tr0_ * NPTS + k0 + to0;
  const f16*   ts1 = T + (size_t)tr1_ * NPTS + k0 + to1;
  const int wu = w * 64 * 16;                  // wave-uniform LDS byte base

  auto STAGE = [&](int kt, int slot) {
    char* xb = lds + slot * 16384;
    char* tb = xb + 8192;
    const int kk = kt * 32;
    gload16(xs0 + kk, xb + wu);
    gload16(xs1 + kk, xb + 4096 + wu);
    gload16(ts0 + kk, tb + wu);
    gload16(ts1 + kk, tb + 4096 + wu);
  };

  f32x4 acc[8];
#pragma unroll
  for (int i = 0; i < 8; ++i) acc[i] = (f32x4){0.f, 0.f, 0.f, 0.f};

  // swizzled read offsets (lane-constant across kt)
  const int axr = w * 16 + rl;  // x_tile row for this lane's A fragment
  const int ad0 = (axr * 8 + ((2 * hi) ^ (axr & 7))) * 16;
  const int ad1 = (axr * 8 + ((2 * hi + 1) ^ (axr & 7))) * 16;
  int bd[8];
#pragma unroll
  for (int ct = 0; ct < 8; ++ct) {
    int trow = ct * 16 + rl;
    bd[ct] = (trow * 4 + (hi ^ (trow & 3))) * 16;
  }

  auto COMPUTE = [&](int slot) {
    char* xb = lds + slot * 16384;
    char* tb = xb + 8192;
    f32x4 a0 = *(const f32x4*)(xb + ad0);
    f32x4 a1 = *(const f32x4*)(xb + ad1);
    f16x8 af;
#pragma unroll
    for (int j = 0; j < 4; ++j) { af[j] = (f16)a0[j]; af[4 + j] = (f16)a1[j]; }
#pragma unroll
    for (int ct = 0; ct < 8; ++ct) {
      f16x8 bf = *(const f16x8*)(tb + bd[ct]);
      acc[ct] = __builtin_amdgcn_mfma_f32_16x16x32_f16(af, bf, acc[ct], 0, 0, 0);
    }
  };

  STAGE(0, 0);
  STAGE(1, 1);
  asm volatile("s_waitcnt vmcnt(4)" ::: "memory");  // slot0 landed; slot1 in flight
  __builtin_amdgcn_s_barrier();

  int sc = 0, ss = 2;  // compute slot, stage slot
  for (int kt = 0; kt < 16; ++kt) {
    if (kt + 2 < 16) STAGE(kt + 2, ss);
    COMPUTE(sc);
    if (kt < 15) {
      if (kt + 2 < 16)
        asm volatile("s_waitcnt vmcnt(4)" ::: "memory");  // next slot landed
      else
        asm volatile("s_waitcnt vmcnt(0)" ::: "memory");  // drain final stage
      __builtin_amdgcn_s_barrier();
    }
    sc = (sc == 2) ? 0 : sc + 1;
    ss = (ss == 2) ? 0 : ss + 1;
  }

  // epilogue: wave w owns rows r0+w*16..+16 (C/D map: row=hi*4+i, col=ct*16+rl)
  float* out = Sp + ((size_t)kb * ROWS + r0 + w * 16) * 128;
#pragma unroll
  for (int ct = 0; ct < 8; ++ct)
#pragma unroll
    for (int i = 0; i < 4; ++i)
      out[(hi * 4 + i) * 128 + ct * 16 + rl] = acc[ct][i];
}

// ---------------------------------------------------------------------------
// Kernel 3a: split-K partial reduction, fully data-parallel.
// ---------------------------------------------------------------------------
__global__ __launch_bounds__(256) void reduce_k(const float* __restrict__ Sp,
                                                float* __restrict__ Sred) {
  const int idx = blockIdx.x * 256 + threadIdx.x;      // 0..65535 float4 idx
  const f32x4* src = (const f32x4*)Sp;
  f32x4 acc = src[idx];
#pragma unroll
  for (int s = 1; s < KB_SPLIT; ++s)
    acc += src[(size_t)s * (ROWS * 128 / 4) + idx];
  ((f32x4*)Sred)[idx] = acc;
}

// ---------------------------------------------------------------------------
// Kernel 3b: channel mix + scaling -> Qh (f16).  Grid: 32 batches x 16 o-groups.
// ---------------------------------------------------------------------------
__global__ __launch_bounds__(256) void mix3(const float* __restrict__ Sred,
                                            const float* __restrict__ Ur,
                                            const float* __restrict__ Ui,
                                            const float* __restrict__ Vr,
                                            const float* __restrict__ Vi,
                                            const float* __restrict__ Sv,
                                            f16* __restrict__ Qh) {
  __shared__ float Srs[64][64], Sis[64][64];
  __shared__ float wr_s[64][4], wi_s[64][4];
  const int b  = blockIdx.x >> 4;
  const int og = blockIdx.x & 15;
  const int t  = threadIdx.x;

#pragma unroll
  for (int j = 0; j < 8; ++j) {
    int f4 = t + 256 * j;                // 0..2047 float4s
    int i = f4 >> 5, kc = (f4 & 31) * 4; // row i, col kc..kc+3
    f32x4 v = *(const f32x4*)(Sred + ((size_t)(b * 64 + i)) * 128 + kc);
    if (kc < 64) *(f32x4*)&Srs[i][kc] = v;
    else         *(f32x4*)&Sis[i][kc - 64] = v;
  }

  {
    int i = t >> 2, ol = t & 3, o = og * 4 + ol;
    float wr = 0.f, wi = 0.f;
#pragma unroll
    for (int r = 0; r < RANKK; ++r) {
      float ur = Ur[i * RANKK + r], ui = Ui[i * RANKK + r];
      float vr = Vr[r * COUT + o],  vi = Vi[r * COUT + o];
      float s = Sv[r];
      wr += s * (ur * vr - ui * vi);
      wi += s * (ur * vi + ui * vr);
    }
    wr_s[i][ol] = wr;
    wi_s[i][ol] = wi;
  }
  __syncthreads();

  const int ol = t >> 6, k = t & 63, o = og * 4 + ol;
  float qr = 0.f, qi = 0.f;
#pragma unroll 4
  for (int i = 0; i < 64; ++i) {
    float sr = Srs[i][k], si = Sis[i][k];     // stride-1 across lanes: conflict-free
    float wr = wr_s[i][ol], wi = wi_s[i][ol]; // wave-uniform broadcast
    qr += sr * wr + si * wi;
    qi += sr * wi - si * wr;
  }
  float sk = (k == 0 ? 1.0f : 2.0f) / (float)NPTS;  // c_k and both ortho 1/sqrt(N)
  f16* qrow = Qh + ((size_t)(b * 64 + o)) * 128;
  qrow[k]      = (f16)(qr * sk);
  qrow[64 + k] = (f16)(-qi * sk);
}

// ---------------------------------------------------------------------------
// Kernel 4: inverse GEMM, block-tiled, PLAIN reg-staged LDS (no swizzle).
//   y[row][n] = sum_c Qh[row][c] * Tt[n][c]
// Grid = 32 row-blocks x 128 n-blocks. Block: 4 waves, tile 64 rows x 64 n.
// B tile: global->VGPR->ds_write into padded Bt[64][136]; reads are plain.
// Epilogue: padded per-wave transpose Tr[4][16][68] -> float4 stores (256 B).
// ---------------------------------------------------------------------------
__global__ __launch_bounds__(256) void inv_dft(const f16* __restrict__ Qh,
                                               const f16* __restrict__ Tt,
                                               float* __restrict__ y) {
  __shared__ f16   Bt[64][136];    // 64 n-rows x 128 k  (+8 f16 pad)
  __shared__ float Tr[4][16][68];  // per-wave store transpose (+4 pad)
  const int t = threadIdx.x, w = t >> 6, lane = t & 63;
  const int rl = lane & 15, hi = lane >> 4;
  const int nb = blockIdx.x & 127;   // n-block (64 wide)
  const int rb = blockIdx.x >> 7;    // row-block (64 rows)
  const int n0 = nb * 64, r0 = rb * 64;

  // stage B tile: 1024 chunks of 8 f16; thread t takes chunks t+256j (coalesced)
  f16x8 stg[4];
#pragma unroll
  for (int j = 0; j < 4; ++j) {
    int d = j * 256 + t, row = d >> 4, q = d & 15;
    stg[j] = *(const f16x8*)(Tt + (size_t)(n0 + row) * 128 + q * 8);
  }
  // A fragments: rows r0 + w*16 + rl, k = 32*ksv + 8*hi (+j)
  const f16* qrow = Qh + (size_t)(r0 + w * 16 + rl) * 128 + 8 * hi;
  f16x8 af[4];
#pragma unroll
  for (int ksv = 0; ksv < 4; ++ksv) af[ksv] = *(const f16x8*)(qrow + ksv * 32);
#pragma unroll
  for (int j = 0; j < 4; ++j) {
    int d = j * 256 + t, row = d >> 4, q = d & 15;
    *(f16x8*)(&Bt[row][q * 8]) = stg[j];
  }
  __syncthreads();

  f32x4 acc[4];
#pragma unroll
  for (int i = 0; i < 4; ++i) acc[i] = (f32x4){0.f, 0.f, 0.f, 0.f};

#pragma unroll
  for (int ksv = 0; ksv < 4; ++ksv)
#pragma unroll
    for (int s = 0; s < 4; ++s) {
      f16x8 bf = *(const f16x8*)(&Bt[s * 16 + rl][(ksv * 4 + hi) * 8]);
      acc[s] = __builtin_amdgcn_mfma_f32_16x16x32_f16(af[ksv], bf, acc[s], 0, 0, 0);
    }

  // epilogue: per-wave transpose in padded LDS, then coalesced float4 stores.
  // C/D map: local row r = hi*4+i, n-local = s*16+rl.  Same-wave ds ordering
  // (write then read) is program-order safe; regions are per-wave disjoint.
#pragma unroll
  for (int s = 0; s < 4; ++s)
#pragma unroll
    for (int i = 0; i < 4; ++i)
      Tr[w][hi * 4 + i][s * 16 + rl] = acc[s][i];
#pragma unroll
  for (int p = 0; p < 4; ++p) {
    int r = p * 4 + hi;
    f32x4 v = *(const f32x4*)(&Tr[w][r][rl * 4]);
    *(f32x4*)(y + (size_t)(r0 + w * 16 + r) * NPTS + n0 + rl * 4) = v;
  }
}

// ---------------------------------------------------------------------------
extern "C" void kernel_launch(void* const* d_in, const int* in_sizes, int n_in,
                              void* d_out, int out_size, void* d_ws, size_t ws_size,
                              hipStream_t stream) {
  const float* x  = (const float*)d_in[0];
  const float* Ur = (const float*)d_in[1];
  const float* Ui = (const float*)d_in[2];
  const float* Vr = (const float*)d_in[3];
  const float* Vi = (const float*)d_in[4];
  const float* Sv = (const float*)d_in[5];
  float* y = (float*)d_out;
  char* ws = (char*)d_ws;

  // workspace layout (21.5 MiB total):
  f16*   T    = (f16*)ws;                              // 2 MiB
  f16*   Tt   = (f16*)(ws + (2u << 20));               // 2 MiB
  float* Sp   = (float*)(ws + (4u << 20));             // KB_SPLIT * 1 MiB
  char*  p    = ws + (4u << 20) + (size_t)KB_SPLIT * ROWS * 128 * 4;
  float* Sred = (float*)p;                             // 1 MiB
  f16*   Qh   = (f16*)(p + (size_t)ROWS * 128 * 4);    // 512 KiB

  build_tables<<<NPTS / 16, 256, 0, stream>>>(T, Tt);
  fwd_dft<<<(ROWS / 64) * KB_SPLIT, 256, 0, stream>>>(x, T, Sp);
  reduce_k<<<ROWS * 128 / 4 / 256, 256, 0, stream>>>(Sp, Sred);
  mix3<<<BATCH * 16, 256, 0, stream>>>(Sred, Ur, Ui, Vr, Vi, Sv, Qh);
  inv_dft<<<(ROWS / 64) * (NPTS / 64), 256, 0, stream>>>(Qh, Tt, y);
}